// Round 12
// baseline (354.817 us; speedup 1.0000x reference)
//
#include <hip/hip_runtime.h>

typedef unsigned short u16;
typedef short s16x8 __attribute__((ext_vector_type(8)));
typedef _Float16 h16x8 __attribute__((ext_vector_type(8)));
typedef float f32x4 __attribute__((ext_vector_type(4)));
typedef u16 u16x4 __attribute__((ext_vector_type(4)));

#define DEV static __device__ __forceinline__

// ---------- f16 limb helpers (RTNE via v_cvt_f16_f32) ----------
DEV u16 f2h(float x){ union { _Float16 h; u16 u; } v; v.h = (_Float16)x; return v.u; }
DEV float h2f(u16 u){ union { u16 u; _Float16 h; } v; v.u = u; return (float)v.h; }
DEV void split_h(float x, u16& h, u16& l){
    h = f2h(x);
    l = f2h(x - h2f(h));
}
DEV h16x8 H8(s16x8 v){ union { s16x8 s; h16x8 h; } u; u.s = v; return u.h; }
DEV f32x4 mfma16(s16x8 a, s16x8 b, f32x4 c){
    return __builtin_amdgcn_mfma_f32_16x16x32_f16(H8(a), H8(b), c, 0, 0, 0);
}

// ---------- t-layout chunk swizzle (bits 3-5 of m XOR row&7) ----------
DEV int swz(int r, int m){ return (m & ~0x38) | ((((m >> 3) ^ r) & 7) << 3); }

// global -> LDS direct (16B per lane)
DEV void gll16(const u16* g, u16* l){
    __builtin_amdgcn_global_load_lds((const __attribute__((address_space(1))) void*)g,
                                     (__attribute__((address_space(3))) void*)l, 16, 0, 0);
}

// =====================================================================
// K_prep (merged): blocks 0..2047 = supports softmax rows; rest =
// weight/bias/lin_w prep. X^T pack moved to k_packx (coalesced).
// =====================================================================
__global__ __launch_bounds__(256) void k_prep(const float* __restrict__ E,
    const float* __restrict__ gwp, const float* __restrict__ gbp,
    const float* __restrict__ uwp, const float* __restrict__ ubp,
    const float* __restrict__ lw,
    u16* __restrict__ wg, u16* __restrict__ wu,
    float* __restrict__ bg, float* __restrict__ bu,
    u16* __restrict__ lwt,
    u16* __restrict__ Sh, u16* __restrict__ Sl)
{
    __shared__ float red[8];
    const int tid = threadIdx.x;
    if (blockIdx.x < 2048){
        const int n = blockIdx.x;
        const int w = tid >> 6, lane = tid & 63;
        float en[10];
        #pragma unroll
        for (int d = 0; d < 10; d++) en[d] = E[n*10 + d];
        float v[8];
        #pragma unroll
        for (int i = 0; i < 8; i++){
            int m = tid + i*256;
            const float* em = E + m*10;
            float s = 0.f;
            #pragma unroll
            for (int d = 0; d < 10; d++) s += en[d]*em[d];
            v[i] = fmaxf(s, 0.f);
        }
        float mx = v[0];
        #pragma unroll
        for (int i = 1; i < 8; i++) mx = fmaxf(mx, v[i]);
        #pragma unroll
        for (int off = 32; off > 0; off >>= 1) mx = fmaxf(mx, __shfl_xor(mx, off));
        if (lane == 0) red[w] = mx;
        __syncthreads();
        mx = fmaxf(fmaxf(red[0], red[1]), fmaxf(red[2], red[3]));
        __syncthreads();
        float sum = 0.f;
        #pragma unroll
        for (int i = 0; i < 8; i++){ v[i] = __expf(v[i] - mx); sum += v[i]; }
        #pragma unroll
        for (int off = 32; off > 0; off >>= 1) sum += __shfl_xor(sum, off);
        if (lane == 0) red[4 + w] = sum;
        __syncthreads();
        sum = red[4] + red[5] + red[6] + red[7];
        float inv = 1.f / sum;
        #pragma unroll
        for (int i = 0; i < 8; i++){
            float p = v[i] * inv;
            u16 h, l; split_h(p, h, l);
            int ms = swz(n, tid + i*256);
            Sh[n*2048 + ms] = h;
            Sl[n*2048 + ms] = l;
        }
        return;
    }
    long idx = (long)(blockIdx.x - 2048)*256 + tid;
    if (idx < 491520){                               // gate w -> [jc][d][128 o][32 k]
        int kk = (int)(idx & 31);
        int o  = (int)((idx >> 5) & 127);
        int r2 = (int)(idx >> 12);                   // 0..119
        int d = r2 % 10, jc = r2 / 10;
        int j = jc*32 + kk;                          // 0..383
        int k = j >> 7, i = j & 127;
        float v = gwp[(((d*3 + k)*128) + i)*128 + o];
        wg[idx] = f2h(v);
    } else if (idx < 737280){                        // upd w -> [jc][d][64 o][32 k]
        long t = idx - 491520;
        int kk = (int)(t & 31);
        int o  = (int)((t >> 5) & 63);
        int r2 = (int)(t >> 11);                     // 0..119
        int d = r2 % 10, jc = r2 / 10;
        int j = jc*32 + kk;
        int k = j >> 7, i = j & 127;
        float v = uwp[(((d*3 + k)*128) + i)*64 + o];
        wu[t] = f2h(v);
    } else if (idx < 999424){                        // bias_g [2048][128]
        long t = idx - 737280; int n = (int)(t >> 7), o = (int)(t & 127);
        float s = 0.f;
        #pragma unroll
        for (int d = 0; d < 10; d++) s += E[n*10+d]*gbp[d*128+o];
        bg[t] = s;
    } else if (idx < 1130496){                       // bias_u [2048][64]
        long t = idx - 999424; int n = (int)(t >> 6), o = (int)(t & 63);
        float s = 0.f;
        #pragma unroll
        for (int d = 0; d < 10; d++) s += E[n*10+d]*ubp[d*64+o];
        bu[t] = s;
    } else if (idx < 1138688){                       // lin_w [64 o][128 k] -> f16
        long t = idx - 1130496;
        lwt[t] = f2h(lw[t]);
    }
}

// =====================================================================
// k_packx: X_gate^T pack, coalesced. Old path: adjacent threads read
// x[m*64+c] at consecutive m, fixed c = one 64B line PER LANE (64x
// over-fetch). New: per block = [64 colG x 256 m] tile; f32x4 c-major
// coalesced reads -> LDS transpose ([64 c][264 m] pad) -> 16B
// swizzled-chunk writes (permutation within 512B window = coalesced).
// Values identical (same f2h) -> Xt bit-identical.
// =====================================================================
__global__ __launch_bounds__(256) void k_packx(const float* __restrict__ x,
                                               const float* __restrict__ state,
                                               u16* __restrict__ xt)
{
    __shared__ u16 T[64*264];
    const int tid = threadIdx.x;
    const int ct = blockIdx.x & 31;        // colG tile (64 wide)
    const int mt = blockIdx.x >> 5;        // m tile (256 tall)
    const int colG0 = ct << 6;
    const int m0 = mt << 8;
    const int b = colG0 >> 7, c0 = colG0 & 127;     // c0 in {0, 64}
    const float* src = (c0 < 64) ? (x + ((long)b*2048 + m0)*64)
                                 : (state + ((long)b*2048 + m0)*64);
    // read: 256 m x 64 c; thread reads f32x4 at (m = p*16 + tid>>4, c4=(tid&15)*4)
    #pragma unroll
    for (int p = 0; p < 16; p++){
        int m = p*16 + (tid >> 4);
        int c4 = (tid & 15) << 2;
        f32x4 v = *(const f32x4*)(src + (long)m*64 + c4);
        #pragma unroll
        for (int q = 0; q < 4; q++)
            T[(c4 + q)*264 + m] = f2h(v[q]);
    }
    __syncthreads();
    // write: thread t, pass p: colG = colG0 + (t>>5) + p*8; m-chunk = (t&31)*8
    #pragma unroll
    for (int p = 0; p < 8; p++){
        int cg = (tid >> 5) + p*8;
        int colG = colG0 + cg;
        int mc = (tid & 31) << 3;
        s16x8 val = *(const s16x8*)&T[cg*264 + mc];
        int ms = swz(colG, m0 + mc);
        *(s16x8*)(xt + (long)colG*2048 + ms) = val;
    }
}

// =====================================================================
// Diffusion GEMM (round-6 proven, VERBATIM — five alternates all null
// or regressed: staging-swizzle r7, A-in-regs r8, K-split r9, 32x32 r10).
// =====================================================================
template<int EPI>
__global__ __launch_bounds__(256) void k_gemm(
    const u16* __restrict__ Ah, const u16* __restrict__ Al,
    const u16* __restrict__ Bt,
    u16* __restrict__ Ot, float* __restrict__ Orow,
    const u16* __restrict__ Xt)
{
    __shared__ __attribute__((aligned(16))) u16 AsH[2][64*64];
    __shared__ __attribute__((aligned(16))) u16 AsL[2][64*64];
    __shared__ __attribute__((aligned(16))) u16 Bs[2][128*64];
    const int tid = threadIdx.x;
    const int xc = blockIdx.x & 7, ii = blockIdx.x >> 3;
    const int bm = ((xc & 3)*8 + (ii & 7)) << 6;     // 32 row-tiles
    const int bn = ((xc >> 2)*8 + (ii >> 3)) << 7;   // 16 col-tiles
    const int w = tid >> 6, lane = tid & 63;
    const int wm = (w & 1) << 5;                     // 32 rows per wave
    const int wn = (w >> 1) << 6;                    // 64 cols per wave
    const int lr = lane & 15, lk = lane >> 4;

    const int srow = tid >> 3, scol = (tid & 7) << 3;
    const long a0 = (long)(bm + srow)*2048 + scol;
    const long a1 = a0 + 32*2048;
    const long b0 = (long)(bn + srow)*2048 + scol;
    const long b1 = b0 + 32*2048;
    const long b2 = b0 + 64*2048;
    const long b3 = b0 + 96*2048;
    const int l0 = tid*8, l1 = tid*8 + 2048;

    const int c0 = (lk ^ (lr & 7)) << 3;
    const int c1 = c0 ^ 32;

#define STAGE(B, K) do { \
        gll16(Ah + a0 + (K), &AsH[B][l0]); \
        gll16(Ah + a1 + (K), &AsH[B][l1]); \
        gll16(Al + a0 + (K), &AsL[B][l0]); \
        gll16(Al + a1 + (K), &AsL[B][l1]); \
        gll16(Bt + b0 + (K), &Bs[B][l0]); \
        gll16(Bt + b1 + (K), &Bs[B][l1]); \
        gll16(Bt + b2 + (K), &Bs[B][l0 + 4096]); \
        gll16(Bt + b3 + (K), &Bs[B][l1 + 4096]); \
    } while(0)

    f32x4 acc[2][4];
    const f32x4 Z4 = {0.f, 0.f, 0.f, 0.f};
    #pragma unroll
    for (int i = 0; i < 2; i++)
        #pragma unroll
        for (int j = 0; j < 4; j++) acc[i][j] = Z4;

    STAGE(0, 0);
    __syncthreads();
    int cur = 0;
    for (int k0 = 0; k0 < 2048; k0 += 64){
        if (k0 + 64 < 2048) STAGE(cur ^ 1, k0 + 64);
        const u16* ah = AsH[cur];
        const u16* al = AsL[cur];
        const u16* bs = Bs[cur];
        #pragma unroll
        for (int s2 = 0; s2 < 2; s2++){
            const int cc = s2 ? c1 : c0;
            s16x8 bfv[4], af[2];
            #pragma unroll
            for (int ni = 0; ni < 4; ni++)
                bfv[ni] = *(const s16x8*)&bs[(wn + ni*16 + lr)*64 + cc];
            #pragma unroll
            for (int mi = 0; mi < 2; mi++)
                af[mi] = *(const s16x8*)&ah[(wm + mi*16 + lr)*64 + cc];
            #pragma unroll
            for (int mi = 0; mi < 2; mi++)
                #pragma unroll
                for (int ni = 0; ni < 4; ni++)
                    acc[mi][ni] = mfma16(af[mi], bfv[ni], acc[mi][ni]);
            #pragma unroll
            for (int mi = 0; mi < 2; mi++)
                af[mi] = *(const s16x8*)&al[(wm + mi*16 + lr)*64 + cc];
            #pragma unroll
            for (int mi = 0; mi < 2; mi++)
                #pragma unroll
                for (int ni = 0; ni < 4; ni++)
                    acc[mi][ni] = mfma16(af[mi], bfv[ni], acc[mi][ni]);
        }
        __syncthreads();
        cur ^= 1;
    }
#undef STAGE

    #pragma unroll
    for (int mi = 0; mi < 2; mi++){
        #pragma unroll
        for (int ni = 0; ni < 4; ni++){
            int i0 = bm + wm + mi*16 + lk*4;
            int j  = bn + wn + ni*16 + lr;
            f32x4 v = acc[mi][ni];
            if constexpr (EPI){
                u16x4 xh = *(const u16x4*)(Xt + (long)j*2048 + swz(j, i0));
                #pragma unroll
                for (int r = 0; r < 4; r++)
                    v[r] = 2.f*v[r] - h2f(xh[r]);
            }
            int bb = j >> 7, cc = j & 127;
            float* rp = Orow + ((long)bb*2048 + i0)*128 + cc;
            #pragma unroll
            for (int r = 0; r < 4; r++) rp[(long)r*128] = v[r];
            if constexpr (!EPI){
                u16x4 oh;
                #pragma unroll
                for (int r = 0; r < 4; r++) oh[r] = f2h(v[r]);
                *(u16x4*)(Ot + (long)j*2048 + swz(j, i0)) = oh;
            }
        }
    }
}

// =====================================================================
// Gate combine (round-11 proven, 512 thr / 8 waves, o-split) + setprio
// around the MFMA cluster (T5). absmax canary 0.01513672.
// =====================================================================
__global__ __launch_bounds__(512) void k_combineG(
    const float* __restrict__ G1r, const float* __restrict__ G2r,
    const float* __restrict__ x, const float* __restrict__ second,
    const u16* __restrict__ W,
    const float* __restrict__ bias, const float* __restrict__ E,
    float* __restrict__ out, u16* __restrict__ XtT,
    const u16* __restrict__ lwt, const float* __restrict__ lb)
{
    __shared__ u16 Ash[64*40], Asl[64*40];
    __shared__ float Et[640];
    __shared__ u16 Zh[64*136], Zl[64*136];
    const int tid = threadIdx.x, bid = blockIdx.x;
    const int b = bid >> 5, n0 = (bid & 31) << 6;
    const int w = tid >> 6, lane = tid & 63;
    const int wo = w << 4;                        // wave's 16-o stripe
    const int lr = lane & 15, lk = lane >> 4;

    for (int i = tid; i < 640; i += 512)
        Et[i] = E[(n0 + (i & 63))*10 + (i >> 6)];

    const f32x4 Z4 = {0.f, 0.f, 0.f, 0.f};
    f32x4 acc[4];
    #pragma unroll
    for (int mi = 0; mi < 4; mi++) acc[mi] = Z4;

    const long rowbase = (long)b*2048 + n0;
    const int laneoff = (wo + lr)*32 + lk*8;      // u16 offset within W tile

    s16x8 pbh[3];

    for (int jc = 0; jc < 12; jc++){
        {
            const long t0 = (long)(jc*10 + 0)*128*32;
            const long t1 = (long)(jc*10 + 1)*128*32;
            pbh[0] = *(const s16x8*)(W + t0 + laneoff);
            pbh[1] = *(const s16x8*)(W + t1 + laneoff);
        }
        __syncthreads();   // prior jc's A-frag reads done
        // ---- stage A (512 thr: one f32x4 per thread) ----
        {
            const float* src; int stride;
            if (jc < 4){
                int col0 = jc*32;
                src = (col0 < 64) ? (x + rowbase*64 + col0)
                                  : (second + rowbase*64 + (col0 - 64));
                stride = 64;
            } else if (jc < 8){
                src = G1r + rowbase*128 + (jc-4)*32; stride = 128;
            } else {
                src = G2r + rowbase*128 + (jc-8)*32; stride = 128;
            }
            int row = tid >> 3, c4 = (tid & 7)*4;
            f32x4 s0 = *(const f32x4*)(src + (long)row*stride + c4);
            u16x4 vh, vl;
            #pragma unroll
            for (int t = 0; t < 4; t++){
                u16 h,l; split_h(s0[t], h, l); vh[t]=h; vl[t]=l;
            }
            *(u16x4*)&Ash[row*40 + c4] = vh;
            *(u16x4*)&Asl[row*40 + c4] = vl;
        }
        __syncthreads();

        s16x8 ah[4], al[4];
        #pragma unroll
        for (int mi = 0; mi < 4; mi++){
            ah[mi] = *(const s16x8*)&Ash[(mi*16 + lr)*40 + lk*8];
            al[mi] = *(const s16x8*)&Asl[(mi*16 + lr)*40 + lk*8];
        }

        #pragma unroll
        for (int d = 0; d < 10; d++){
            const int cur = d % 3;
            if (d < 8){
                const int nx = (d + 2) % 3;
                const long t2 = (long)(jc*10 + d + 2)*128*32;
                pbh[nx] = *(const s16x8*)(W + t2 + laneoff);
            }
            f32x4 Cd[4];
            __builtin_amdgcn_s_setprio(1);
            #pragma unroll
            for (int mi = 0; mi < 4; mi++)
                Cd[mi] = mfma16(ah[mi], pbh[cur], Z4);
            #pragma unroll
            for (int mi = 0; mi < 4; mi++)
                Cd[mi] = mfma16(al[mi], pbh[cur], Cd[mi]);
            __builtin_amdgcn_s_setprio(0);
            #pragma unroll
            for (int mi = 0; mi < 4; mi++){
                f32x4 e4 = *(const f32x4*)&Et[d*64 + mi*16 + lk*4];
                acc[mi] += e4 * Cd[mi];
            }
        }
    }

    // ---- fused: Zg = sigmoid(acc+bias) -> LDS limbs ----
    #pragma unroll
    for (int mi = 0; mi < 4; mi++){
        int lrow = mi*16 + lk*4;
        int o = wo + lr;
        #pragma unroll
        for (int r = 0; r < 4; r++){
            float v = acc[mi][r] + bias[(long)(n0 + lrow + r)*128 + o];
            v = 1.f/(1.f + __expf(-v));
            u16 h, l; split_h(v, h, l);
            Zh[(lrow + r)*136 + o] = h;
            Zl[(lrow + r)*136 + o] = l;
        }
    }
    __syncthreads();
    // ---- zr = Zg @ lw^T + lb ; wave w: o-stripe (w&3)*16, rows (w>>2)*32 ----
    f32x4 az[2] = {Z4, Z4};
    const int ow = (w & 3) << 4;
    const int rh = (w >> 2) << 5;
    #pragma unroll
    for (int ks = 0; ks < 4; ks++){
        s16x8 bw = *(const s16x8*)(lwt + (ow + lr)*128 + ks*32 + lk*8);
        #pragma unroll
        for (int mi = 0; mi < 2; mi++){
            s16x8 zh = *(const s16x8*)&Zh[(rh + mi*16 + lr)*136 + ks*32 + lk*8];
            az[mi] = mfma16(zh, bw, az[mi]);
        }
        #pragma unroll
        for (int mi = 0; mi < 2; mi++){
            s16x8 zl = *(const s16x8*)&Zl[(rh + mi*16 + lr)*136 + ks*32 + lk*8];
            az[mi] = mfma16(zl, bw, az[mi]);
        }
    }
    const float lbv = lb[ow + lr];
    const int colG = b*128 + 64 + ow + lr;
    #pragma unroll
    for (int mi = 0; mi < 2; mi++){
        int mrow = n0 + rh + mi*16 + lk*4;
        u16x4 tq;
        #pragma unroll
        for (int r = 0; r < 4; r++){
            float v = az[mi][r] + lbv;
            out[((long)b*2048 + mrow + r)*64 + ow + lr] = v;   // zr f32 rows
            tq[r] = f2h(v);
        }
        *(u16x4*)(XtT + (long)colG*2048 + swz(colG, mrow)) = tq; // candidate^T half
    }
}

// =====================================================================
// Update combine v2 (512 thr / 8 waves, r11-pattern): wave w owns
// o-stripe (w&3)*16 x row-half (w>>2)*32 (mi=2). Occupancy 2x vs the
// 256-thr version; W dup unchanged (2x row-half). Per-output MFMA
// sequence identical -> bit-exact. setprio around MFMA cluster.
// =====================================================================
__global__ __launch_bounds__(512) void k_combineU(
    const float* __restrict__ G1r, const float* __restrict__ G2r,
    const float* __restrict__ x, const float* __restrict__ second,
    const u16* __restrict__ W,
    const float* __restrict__ bias, const float* __restrict__ E,
    float* __restrict__ out)
{
    __shared__ u16 Ash[64*40], Asl[64*40];
    __shared__ float Et[640];
    const int tid = threadIdx.x, bid = blockIdx.x;
    const int b = bid >> 5, n0 = (bid & 31) << 6;
    const int w = tid >> 6, lane = tid & 63;
    const int ow = (w & 3) << 4;                  // wave's 16-o stripe
    const int rh = (w >> 2) << 5;                 // wave's 32-row half
    const int lr = lane & 15, lk = lane >> 4;

    for (int i = tid; i < 640; i += 512)
        Et[i] = E[(n0 + (i & 63))*10 + (i >> 6)];

    const f32x4 Z4 = {0.f, 0.f, 0.f, 0.f};
    f32x4 acc[2];
    #pragma unroll
    for (int mi = 0; mi < 2; mi++) acc[mi] = Z4;

    const long rowbase = (long)b*2048 + n0;
    const int laneoff = (ow + lr)*32 + lk*8;      // u16 offset in [64 o][32 k] tile

    s16x8 pbh[3];

    for (int jc = 0; jc < 12; jc++){
        {
            const long t0 = (long)(jc*10 + 0)*64*32;
            const long t1 = (long)(jc*10 + 1)*64*32;
            pbh[0] = *(const s16x8*)(W + t0 + laneoff);
            pbh[1] = *(const s16x8*)(W + t1 + laneoff);
        }
        __syncthreads();
        // ---- stage A (512 thr: one f32x4 per thread) ----
        {
            const float* src; int stride;
            if (jc < 4){
                int col0 = jc*32;
                src = (col0 < 64) ? (x + rowbase*64 + col0)
                                  : (second + rowbase*64 + (col0 - 64));
                stride = 64;
            } else if (jc < 8){
                src = G1r + rowbase*128 + (jc-4)*32; stride = 128;
            } else {
                src = G2r + rowbase*128 + (jc-8)*32; stride = 128;
            }
            int row = tid >> 3, c4 = (tid & 7)*4;
            f32x4 s0 = *(const f32x4*)(src + (long)row*stride + c4);
            u16x4 vh, vl;
            #pragma unroll
            for (int t = 0; t < 4; t++){
                u16 h,l; split_h(s0[t], h, l); vh[t]=h; vl[t]=l;
            }
            *(u16x4*)&Ash[row*40 + c4] = vh;
            *(u16x4*)&Asl[row*40 + c4] = vl;
        }
        __syncthreads();

        s16x8 ah[2], al[2];
        #pragma unroll
        for (int mi = 0; mi < 2; mi++){
            ah[mi] = *(const s16x8*)&Ash[(rh + mi*16 + lr)*40 + lk*8];
            al[mi] = *(const s16x8*)&Asl[(rh + mi*16 + lr)*40 + lk*8];
        }

        #pragma unroll
        for (int d = 0; d < 10; d++){
            const int cur = d % 3;
            if (d < 8){
                const int nx = (d + 2) % 3;
                const long t2 = (long)(jc*10 + d + 2)*64*32;
                pbh[nx] = *(const s16x8*)(W + t2 + laneoff);
            }
            f32x4 Cd[2];
            __builtin_amdgcn_s_setprio(1);
            #pragma unroll
            for (int mi = 0; mi < 2; mi++)
                Cd[mi] = mfma16(ah[mi], pbh[cur], Z4);
            #pragma unroll
            for (int mi = 0; mi < 2; mi++)
                Cd[mi] = mfma16(al[mi], pbh[cur], Cd[mi]);
            __builtin_amdgcn_s_setprio(0);
            #pragma unroll
            for (int mi = 0; mi < 2; mi++){
                f32x4 e4 = *(const f32x4*)&Et[d*64 + rh + mi*16 + lk*4];
                acc[mi] += e4 * Cd[mi];
            }
        }
    }

    #pragma unroll
    for (int mi = 0; mi < 2; mi++){
        int mrow = n0 + rh + mi*16 + lk*4;
        int o = ow + lr;
        #pragma unroll
        for (int r = 0; r < 4; r++){
            float v = acc[mi][r] + bias[(long)(mrow + r)*64 + o];
            v = tanhf(v);
            out[((long)b*2048 + mrow + r)*64 + o] = v;
        }
    }
}

// =====================================================================
extern "C" void kernel_launch(void* const* d_in, const int* in_sizes, int n_in,
                              void* d_out, int out_size, void* d_ws, size_t ws_size,
                              hipStream_t stream)
{
    const float* x   = (const float*)d_in[0];
    const float* st  = (const float*)d_in[1];
    const float* E   = (const float*)d_in[2];
    const float* gwp = (const float*)d_in[3];
    const float* gbp = (const float*)d_in[4];
    const float* uwp = (const float*)d_in[5];
    const float* ubp = (const float*)d_in[6];
    const float* lw  = (const float*)d_in[7];
    const float* lb  = (const float*)d_in[8];
    float* out = (float*)d_out;
    char* ws = (char*)d_ws;

    const size_t MB8 = 8388608;
    u16*   Sh   = (u16*)(ws);                 // 8 MB
    u16*   Sl   = (u16*)(ws + 1*MB8);         // 8 MB
    u16*   Xt   = (u16*)(ws + 2*MB8);         // 8 MB (X^T gate -> candidate)
    u16*   G1t  = (u16*)(ws + 3*MB8);         // 8 MB
    float* G1row= (float*)(ws + 4*MB8);       // 16 MB
    float* G2row= (float*)(ws + 6*MB8);       // 16 MB
    float* zr   = (float*)(ws + 8*MB8);       // 8 MB
    char*  p    = ws + 9*MB8;
    u16* wg = (u16*)p;             p += 983040;
    u16* wu = (u16*)p;             p += 491520;
    float* bg = (float*)p;         p += 1048576;
    float* bu = (float*)p;         p += 524288;
    u16* lwt = (u16*)p;            p += 16384;

    // merged supports (2048 blocks) + prep (4449 blocks)
    k_prep<<<dim3(6497), dim3(256), 0, stream>>>(E, gwp, gbp, uwp, ubp, lw,
                                                 wg, wu, bg, bu, lwt, Sh, Sl);
    // coalesced X^T pack (values bit-identical to old path)
    k_packx<<<dim3(256), dim3(256), 0, stream>>>(x, st, Xt);
    // gate diffusion
    k_gemm<0><<<dim3(512), dim3(256), 0, stream>>>(Sh, Sl, Xt, G1t, G1row,
                                                   (const u16*)nullptr);
    k_gemm<1><<<dim3(512), dim3(256), 0, stream>>>(Sh, Sl, G1t, (u16*)nullptr, G2row,
                                                   Xt);
    // gate combine (512-thr, 8-wave o-split) -> zr + candidate^T into Xt
    k_combineG<<<dim3(512), dim3(512), 0, stream>>>(G1row, G2row, x, st,
                                                    wg, bg, E, zr, Xt, lwt, lb);
    // update diffusion (Xt now = candidate^T)
    k_gemm<0><<<dim3(512), dim3(256), 0, stream>>>(Sh, Sl, Xt, G1t, G1row,
                                                   (const u16*)nullptr);
    k_gemm<1><<<dim3(512), dim3(256), 0, stream>>>(Sh, Sl, G1t, (u16*)nullptr, G2row,
                                                   Xt);
    // update combine (512-thr, 8-wave) -> out (tanh)
    k_combineU<<<dim3(512), dim3(512), 0, stream>>>(G1row, G2row, x, zr,
                                                    wu, bu, E, out);
}

// Round 13
// 337.347 us; speedup vs baseline: 1.0518x; 1.0518x over previous
//
#include <hip/hip_runtime.h>

typedef unsigned short u16;
typedef short s16x8 __attribute__((ext_vector_type(8)));
typedef _Float16 h16x8 __attribute__((ext_vector_type(8)));
typedef float f32x4 __attribute__((ext_vector_type(4)));
typedef u16 u16x4 __attribute__((ext_vector_type(4)));

#define DEV static __device__ __forceinline__

// ---------- f16 limb helpers (RTNE via v_cvt_f16_f32) ----------
DEV u16 f2h(float x){ union { _Float16 h; u16 u; } v; v.h = (_Float16)x; return v.u; }
DEV float h2f(u16 u){ union { u16 u; _Float16 h; } v; v.u = u; return (float)v.h; }
DEV void split_h(float x, u16& h, u16& l){
    h = f2h(x);
    l = f2h(x - h2f(h));
}
DEV h16x8 H8(s16x8 v){ union { s16x8 s; h16x8 h; } u; u.s = v; return u.h; }
DEV f32x4 mfma16(s16x8 a, s16x8 b, f32x4 c){
    return __builtin_amdgcn_mfma_f32_16x16x32_f16(H8(a), H8(b), c, 0, 0, 0);
}

// ---------- t-layout chunk swizzle (bits 3-5 of m XOR row&7) ----------
DEV int swz(int r, int m){ return (m & ~0x38) | ((((m >> 3) ^ r) & 7) << 3); }

// global -> LDS direct (16B per lane)
DEV void gll16(const u16* g, u16* l){
    __builtin_amdgcn_global_load_lds((const __attribute__((address_space(1))) void*)g,
                                     (__attribute__((address_space(3))) void*)l, 16, 0, 0);
}

// =====================================================================
// K_prep (merged): blocks 0..2047 = supports softmax rows; rest =
// weight/bias/lin_w prep.
// =====================================================================
__global__ __launch_bounds__(256) void k_prep(const float* __restrict__ E,
    const float* __restrict__ gwp, const float* __restrict__ gbp,
    const float* __restrict__ uwp, const float* __restrict__ ubp,
    const float* __restrict__ lw,
    u16* __restrict__ wg, u16* __restrict__ wu,
    float* __restrict__ bg, float* __restrict__ bu,
    u16* __restrict__ lwt,
    u16* __restrict__ Sh, u16* __restrict__ Sl)
{
    __shared__ float red[8];
    const int tid = threadIdx.x;
    if (blockIdx.x < 2048){
        const int n = blockIdx.x;
        const int w = tid >> 6, lane = tid & 63;
        float en[10];
        #pragma unroll
        for (int d = 0; d < 10; d++) en[d] = E[n*10 + d];
        float v[8];
        #pragma unroll
        for (int i = 0; i < 8; i++){
            int m = tid + i*256;
            const float* em = E + m*10;
            float s = 0.f;
            #pragma unroll
            for (int d = 0; d < 10; d++) s += en[d]*em[d];
            v[i] = fmaxf(s, 0.f);
        }
        float mx = v[0];
        #pragma unroll
        for (int i = 1; i < 8; i++) mx = fmaxf(mx, v[i]);
        #pragma unroll
        for (int off = 32; off > 0; off >>= 1) mx = fmaxf(mx, __shfl_xor(mx, off));
        if (lane == 0) red[w] = mx;
        __syncthreads();
        mx = fmaxf(fmaxf(red[0], red[1]), fmaxf(red[2], red[3]));
        __syncthreads();
        float sum = 0.f;
        #pragma unroll
        for (int i = 0; i < 8; i++){ v[i] = __expf(v[i] - mx); sum += v[i]; }
        #pragma unroll
        for (int off = 32; off > 0; off >>= 1) sum += __shfl_xor(sum, off);
        if (lane == 0) red[4 + w] = sum;
        __syncthreads();
        sum = red[4] + red[5] + red[6] + red[7];
        float inv = 1.f / sum;
        #pragma unroll
        for (int i = 0; i < 8; i++){
            float p = v[i] * inv;
            u16 h, l; split_h(p, h, l);
            int ms = swz(n, tid + i*256);
            Sh[n*2048 + ms] = h;
            Sl[n*2048 + ms] = l;
        }
        return;
    }
    long idx = (long)(blockIdx.x - 2048)*256 + tid;
    if (idx < 491520){                               // gate w -> [jc][d][128 o][32 k]
        int kk = (int)(idx & 31);
        int o  = (int)((idx >> 5) & 127);
        int r2 = (int)(idx >> 12);                   // 0..119
        int d = r2 % 10, jc = r2 / 10;
        int j = jc*32 + kk;                          // 0..383
        int k = j >> 7, i = j & 127;
        float v = gwp[(((d*3 + k)*128) + i)*128 + o];
        wg[idx] = f2h(v);
    } else if (idx < 737280){                        // upd w -> [jc][d][64 o][32 k]
        long t = idx - 491520;
        int kk = (int)(t & 31);
        int o  = (int)((t >> 5) & 63);
        int r2 = (int)(t >> 11);                     // 0..119
        int d = r2 % 10, jc = r2 / 10;
        int j = jc*32 + kk;
        int k = j >> 7, i = j & 127;
        float v = uwp[(((d*3 + k)*128) + i)*64 + o];
        wu[t] = f2h(v);
    } else if (idx < 999424){                        // bias_g [2048][128]
        long t = idx - 737280; int n = (int)(t >> 7), o = (int)(t & 127);
        float s = 0.f;
        #pragma unroll
        for (int d = 0; d < 10; d++) s += E[n*10+d]*gbp[d*128+o];
        bg[t] = s;
    } else if (idx < 1130496){                       // bias_u [2048][64]
        long t = idx - 999424; int n = (int)(t >> 6), o = (int)(t & 63);
        float s = 0.f;
        #pragma unroll
        for (int d = 0; d < 10; d++) s += E[n*10+d]*ubp[d*64+o];
        bu[t] = s;
    } else if (idx < 1138688){                       // lin_w [64 o][128 k] -> f16
        long t = idx - 1130496;
        lwt[t] = f2h(lw[t]);
    }
}

// =====================================================================
// k_packx: X_gate^T pack, coalesced (round-12 proven).
// =====================================================================
__global__ __launch_bounds__(256) void k_packx(const float* __restrict__ x,
                                               const float* __restrict__ state,
                                               u16* __restrict__ xt)
{
    __shared__ u16 T[64*264];
    const int tid = threadIdx.x;
    const int ct = blockIdx.x & 31;        // colG tile (64 wide)
    const int mt = blockIdx.x >> 5;        // m tile (256 tall)
    const int colG0 = ct << 6;
    const int m0 = mt << 8;
    const int b = colG0 >> 7, c0 = colG0 & 127;     // c0 in {0, 64}
    const float* src = (c0 < 64) ? (x + ((long)b*2048 + m0)*64)
                                 : (state + ((long)b*2048 + m0)*64);
    #pragma unroll
    for (int p = 0; p < 16; p++){
        int m = p*16 + (tid >> 4);
        int c4 = (tid & 15) << 2;
        f32x4 v = *(const f32x4*)(src + (long)m*64 + c4);
        #pragma unroll
        for (int q = 0; q < 4; q++)
            T[(c4 + q)*264 + m] = f2h(v[q]);
    }
    __syncthreads();
    #pragma unroll
    for (int p = 0; p < 8; p++){
        int cg = (tid >> 5) + p*8;
        int colG = colG0 + cg;
        int mc = (tid & 31) << 3;
        s16x8 val = *(const s16x8*)&T[cg*264 + mc];
        int ms = swz(colG, m0 + mc);
        *(s16x8*)(xt + (long)colG*2048 + ms) = val;
    }
}

// =====================================================================
// Diffusion GEMM (round-6 proven structure), templated on NCT = number
// of 128-wide col-tiles (16 = full 2048 colG; 8 = zr-only 1024 colG).
// Update diffusion runs at NCT=8: the x-derived columns of G1/G2 are
// bit-identical to the gate pass's (per-column MFMA independence) and
// are NOT recomputed — combineU reads them from G1row/G2row.
// =====================================================================
template<int EPI, int NCT>
__global__ __launch_bounds__(256) void k_gemm(
    const u16* __restrict__ Ah, const u16* __restrict__ Al,
    const u16* __restrict__ Bt,
    u16* __restrict__ Ot, float* __restrict__ Orow,
    const u16* __restrict__ Xt)
{
    constexpr int COLS = NCT*8;            // row-major output width (128/64)
    constexpr int CSH  = (NCT == 16) ? 7 : 6;
    __shared__ __attribute__((aligned(16))) u16 AsH[2][64*64];
    __shared__ __attribute__((aligned(16))) u16 AsL[2][64*64];
    __shared__ __attribute__((aligned(16))) u16 Bs[2][128*64];
    const int tid = threadIdx.x;
    // XCD-aware bijective tile mapping (8 XCDs; 32 row-tiles x NCT col-tiles)
    const int xc = blockIdx.x & 7, ii = blockIdx.x >> 3;
    const int bm = ((xc & 3)*8 + (ii & 7)) << 6;
    const int bn = ((xc >> 2)*(NCT/2) + (ii >> 3)) << 7;
    const int w = tid >> 6, lane = tid & 63;
    const int wm = (w & 1) << 5;                     // 32 rows per wave
    const int wn = (w >> 1) << 6;                    // 64 cols per wave
    const int lr = lane & 15, lk = lane >> 4;

    const int srow = tid >> 3, scol = (tid & 7) << 3;
    const long a0 = (long)(bm + srow)*2048 + scol;
    const long a1 = a0 + 32*2048;
    const long b0 = (long)(bn + srow)*2048 + scol;
    const long b1 = b0 + 32*2048;
    const long b2 = b0 + 64*2048;
    const long b3 = b0 + 96*2048;
    const int l0 = tid*8, l1 = tid*8 + 2048;

    const int c0 = (lk ^ (lr & 7)) << 3;
    const int c1 = c0 ^ 32;

#define STAGE(B, K) do { \
        gll16(Ah + a0 + (K), &AsH[B][l0]); \
        gll16(Ah + a1 + (K), &AsH[B][l1]); \
        gll16(Al + a0 + (K), &AsL[B][l0]); \
        gll16(Al + a1 + (K), &AsL[B][l1]); \
        gll16(Bt + b0 + (K), &Bs[B][l0]); \
        gll16(Bt + b1 + (K), &Bs[B][l1]); \
        gll16(Bt + b2 + (K), &Bs[B][l0 + 4096]); \
        gll16(Bt + b3 + (K), &Bs[B][l1 + 4096]); \
    } while(0)

    f32x4 acc[2][4];
    const f32x4 Z4 = {0.f, 0.f, 0.f, 0.f};
    #pragma unroll
    for (int i = 0; i < 2; i++)
        #pragma unroll
        for (int j = 0; j < 4; j++) acc[i][j] = Z4;

    STAGE(0, 0);
    __syncthreads();
    int cur = 0;
    for (int k0 = 0; k0 < 2048; k0 += 64){
        if (k0 + 64 < 2048) STAGE(cur ^ 1, k0 + 64);
        const u16* ah = AsH[cur];
        const u16* al = AsL[cur];
        const u16* bs = Bs[cur];
        #pragma unroll
        for (int s2 = 0; s2 < 2; s2++){
            const int cc = s2 ? c1 : c0;
            s16x8 bfv[4], af[2];
            #pragma unroll
            for (int ni = 0; ni < 4; ni++)
                bfv[ni] = *(const s16x8*)&bs[(wn + ni*16 + lr)*64 + cc];
            #pragma unroll
            for (int mi = 0; mi < 2; mi++)
                af[mi] = *(const s16x8*)&ah[(wm + mi*16 + lr)*64 + cc];
            #pragma unroll
            for (int mi = 0; mi < 2; mi++)
                #pragma unroll
                for (int ni = 0; ni < 4; ni++)
                    acc[mi][ni] = mfma16(af[mi], bfv[ni], acc[mi][ni]);
            #pragma unroll
            for (int mi = 0; mi < 2; mi++)
                af[mi] = *(const s16x8*)&al[(wm + mi*16 + lr)*64 + cc];
            #pragma unroll
            for (int mi = 0; mi < 2; mi++)
                #pragma unroll
                for (int ni = 0; ni < 4; ni++)
                    acc[mi][ni] = mfma16(af[mi], bfv[ni], acc[mi][ni]);
        }
        __syncthreads();
        cur ^= 1;
    }
#undef STAGE

    #pragma unroll
    for (int mi = 0; mi < 2; mi++){
        #pragma unroll
        for (int ni = 0; ni < 4; ni++){
            int i0 = bm + wm + mi*16 + lk*4;
            int j  = bn + wn + ni*16 + lr;
            f32x4 v = acc[mi][ni];
            if constexpr (EPI){
                u16x4 xh = *(const u16x4*)(Xt + (long)j*2048 + swz(j, i0));
                #pragma unroll
                for (int r = 0; r < 4; r++)
                    v[r] = 2.f*v[r] - h2f(xh[r]);
            }
            int bb = j >> CSH, cc = j & (COLS-1);
            float* rp = Orow + ((long)bb*2048 + i0)*COLS + cc;
            #pragma unroll
            for (int r = 0; r < 4; r++) rp[(long)r*COLS] = v[r];
            if constexpr (!EPI){
                u16x4 oh;
                #pragma unroll
                for (int r = 0; r < 4; r++) oh[r] = f2h(v[r]);
                *(u16x4*)(Ot + (long)j*2048 + swz(j, i0)) = oh;
            }
        }
    }
}

// =====================================================================
// Gate combine (round-12 proven, 512 thr / 8 waves, o-split, setprio).
// Fused epilogue: zr = Zg@lw^T + lb -> zr f32 rows + Zt (zr^T t-layout
// [1024 colZ][2048 m], swizzled) for the half-width update diffusion.
// absmax canary 0.01513672.
// =====================================================================
__global__ __launch_bounds__(512) void k_combineG(
    const float* __restrict__ G1r, const float* __restrict__ G2r,
    const float* __restrict__ x, const float* __restrict__ second,
    const u16* __restrict__ W,
    const float* __restrict__ bias, const float* __restrict__ E,
    float* __restrict__ out, u16* __restrict__ Zt,
    const u16* __restrict__ lwt, const float* __restrict__ lb)
{
    __shared__ u16 Ash[64*40], Asl[64*40];
    __shared__ float Et[640];
    __shared__ u16 Zh[64*136], Zl[64*136];
    const int tid = threadIdx.x, bid = blockIdx.x;
    const int b = bid >> 5, n0 = (bid & 31) << 6;
    const int w = tid >> 6, lane = tid & 63;
    const int wo = w << 4;                        // wave's 16-o stripe
    const int lr = lane & 15, lk = lane >> 4;

    for (int i = tid; i < 640; i += 512)
        Et[i] = E[(n0 + (i & 63))*10 + (i >> 6)];

    const f32x4 Z4 = {0.f, 0.f, 0.f, 0.f};
    f32x4 acc[4];
    #pragma unroll
    for (int mi = 0; mi < 4; mi++) acc[mi] = Z4;

    const long rowbase = (long)b*2048 + n0;
    const int laneoff = (wo + lr)*32 + lk*8;      // u16 offset within W tile

    s16x8 pbh[3];

    for (int jc = 0; jc < 12; jc++){
        {
            const long t0 = (long)(jc*10 + 0)*128*32;
            const long t1 = (long)(jc*10 + 1)*128*32;
            pbh[0] = *(const s16x8*)(W + t0 + laneoff);
            pbh[1] = *(const s16x8*)(W + t1 + laneoff);
        }
        __syncthreads();   // prior jc's A-frag reads done
        // ---- stage A (512 thr: one f32x4 per thread) ----
        {
            const float* src; int stride;
            if (jc < 4){
                int col0 = jc*32;
                src = (col0 < 64) ? (x + rowbase*64 + col0)
                                  : (second + rowbase*64 + (col0 - 64));
                stride = 64;
            } else if (jc < 8){
                src = G1r + rowbase*128 + (jc-4)*32; stride = 128;
            } else {
                src = G2r + rowbase*128 + (jc-8)*32; stride = 128;
            }
            int row = tid >> 3, c4 = (tid & 7)*4;
            f32x4 s0 = *(const f32x4*)(src + (long)row*stride + c4);
            u16x4 vh, vl;
            #pragma unroll
            for (int t = 0; t < 4; t++){
                u16 h,l; split_h(s0[t], h, l); vh[t]=h; vl[t]=l;
            }
            *(u16x4*)&Ash[row*40 + c4] = vh;
            *(u16x4*)&Asl[row*40 + c4] = vl;
        }
        __syncthreads();

        s16x8 ah[4], al[4];
        #pragma unroll
        for (int mi = 0; mi < 4; mi++){
            ah[mi] = *(const s16x8*)&Ash[(mi*16 + lr)*40 + lk*8];
            al[mi] = *(const s16x8*)&Asl[(mi*16 + lr)*40 + lk*8];
        }

        #pragma unroll
        for (int d = 0; d < 10; d++){
            const int cur = d % 3;
            if (d < 8){
                const int nx = (d + 2) % 3;
                const long t2 = (long)(jc*10 + d + 2)*128*32;
                pbh[nx] = *(const s16x8*)(W + t2 + laneoff);
            }
            f32x4 Cd[4];
            __builtin_amdgcn_s_setprio(1);
            #pragma unroll
            for (int mi = 0; mi < 4; mi++)
                Cd[mi] = mfma16(ah[mi], pbh[cur], Z4);
            #pragma unroll
            for (int mi = 0; mi < 4; mi++)
                Cd[mi] = mfma16(al[mi], pbh[cur], Cd[mi]);
            __builtin_amdgcn_s_setprio(0);
            #pragma unroll
            for (int mi = 0; mi < 4; mi++){
                f32x4 e4 = *(const f32x4*)&Et[d*64 + mi*16 + lk*4];
                acc[mi] += e4 * Cd[mi];
            }
        }
    }

    // ---- fused: Zg = sigmoid(acc+bias) -> LDS limbs ----
    #pragma unroll
    for (int mi = 0; mi < 4; mi++){
        int lrow = mi*16 + lk*4;
        int o = wo + lr;
        #pragma unroll
        for (int r = 0; r < 4; r++){
            float v = acc[mi][r] + bias[(long)(n0 + lrow + r)*128 + o];
            v = 1.f/(1.f + __expf(-v));
            u16 h, l; split_h(v, h, l);
            Zh[(lrow + r)*136 + o] = h;
            Zl[(lrow + r)*136 + o] = l;
        }
    }
    __syncthreads();
    // ---- zr = Zg @ lw^T + lb ; wave w: o-stripe (w&3)*16, rows (w>>2)*32 ----
    f32x4 az[2] = {Z4, Z4};
    const int ow = (w & 3) << 4;
    const int rh = (w >> 2) << 5;
    #pragma unroll
    for (int ks = 0; ks < 4; ks++){
        s16x8 bw = *(const s16x8*)(lwt + (ow + lr)*128 + ks*32 + lk*8);
        #pragma unroll
        for (int mi = 0; mi < 2; mi++){
            s16x8 zh = *(const s16x8*)&Zh[(rh + mi*16 + lr)*136 + ks*32 + lk*8];
            az[mi] = mfma16(zh, bw, az[mi]);
        }
        #pragma unroll
        for (int mi = 0; mi < 2; mi++){
            s16x8 zl = *(const s16x8*)&Zl[(rh + mi*16 + lr)*136 + ks*32 + lk*8];
            az[mi] = mfma16(zl, bw, az[mi]);
        }
    }
    const float lbv = lb[ow + lr];
    const int colZ = b*64 + ow + lr;                 // zr^T row in [0,1024)
    #pragma unroll
    for (int mi = 0; mi < 2; mi++){
        int mrow = n0 + rh + mi*16 + lk*4;
        u16x4 tq;
        #pragma unroll
        for (int r = 0; r < 4; r++){
            float v = az[mi][r] + lbv;
            out[((long)b*2048 + mrow + r)*64 + ow + lr] = v;   // zr f32 rows
            tq[r] = f2h(v);
        }
        *(u16x4*)(Zt + (long)colZ*2048 + swz(colZ, mrow)) = tq; // zr^T t-layout
    }
}

// =====================================================================
// Update combine (round-12 512-thr structure). A-chunk sources remapped:
// x-derived diffusion terms come from the GATE pass's G1row/G2row cols
// 0-63 (bit-identical per-column), zr-derived from half-width G1z/G2z.
// jc: 0-1 x | 2-3 zr | 4-5 G1row(Px) | 6-7 G1z(Pzr) | 8-9 G2row | 10-11 G2z.
// =====================================================================
__global__ __launch_bounds__(512) void k_combineU(
    const float* __restrict__ G1r, const float* __restrict__ G2r,
    const float* __restrict__ G1z, const float* __restrict__ G2z,
    const float* __restrict__ x, const float* __restrict__ zr,
    const u16* __restrict__ W,
    const float* __restrict__ bias, const float* __restrict__ E,
    float* __restrict__ out)
{
    __shared__ u16 Ash[64*40], Asl[64*40];
    __shared__ float Et[640];
    const int tid = threadIdx.x, bid = blockIdx.x;
    const int b = bid >> 5, n0 = (bid & 31) << 6;
    const int w = tid >> 6, lane = tid & 63;
    const int ow = (w & 3) << 4;                  // wave's 16-o stripe
    const int rh = (w >> 2) << 5;                 // wave's 32-row half
    const int lr = lane & 15, lk = lane >> 4;

    for (int i = tid; i < 640; i += 512)
        Et[i] = E[(n0 + (i & 63))*10 + (i >> 6)];

    const f32x4 Z4 = {0.f, 0.f, 0.f, 0.f};
    f32x4 acc[2];
    #pragma unroll
    for (int mi = 0; mi < 2; mi++) acc[mi] = Z4;

    const long rowbase = (long)b*2048 + n0;
    const int laneoff = (ow + lr)*32 + lk*8;      // u16 offset in [64 o][32 k] tile

    s16x8 pbh[3];

    for (int jc = 0; jc < 12; jc++){
        {
            const long t0 = (long)(jc*10 + 0)*64*32;
            const long t1 = (long)(jc*10 + 1)*64*32;
            pbh[0] = *(const s16x8*)(W + t0 + laneoff);
            pbh[1] = *(const s16x8*)(W + t1 + laneoff);
        }
        __syncthreads();
        // ---- stage A (512 thr: one f32x4 per thread) ----
        {
            const float* src; int stride;
            switch (jc >> 1){
                case 0: src = x   + rowbase*64  + (jc&1)*32;  stride = 64;  break;
                case 1: src = zr  + rowbase*64  + (jc&1)*32;  stride = 64;  break;
                case 2: src = G1r + rowbase*128 + (jc&1)*32;  stride = 128; break;
                case 3: src = G1z + rowbase*64  + (jc&1)*32;  stride = 64;  break;
                case 4: src = G2r + rowbase*128 + (jc&1)*32;  stride = 128; break;
                default:src = G2z + rowbase*64  + (jc&1)*32;  stride = 64;  break;
            }
            int row = tid >> 3, c4 = (tid & 7)*4;
            f32x4 s0 = *(const f32x4*)(src + (long)row*stride + c4);
            u16x4 vh, vl;
            #pragma unroll
            for (int t = 0; t < 4; t++){
                u16 h,l; split_h(s0[t], h, l); vh[t]=h; vl[t]=l;
            }
            *(u16x4*)&Ash[row*40 + c4] = vh;
            *(u16x4*)&Asl[row*40 + c4] = vl;
        }
        __syncthreads();

        s16x8 ah[2], al[2];
        #pragma unroll
        for (int mi = 0; mi < 2; mi++){
            ah[mi] = *(const s16x8*)&Ash[(rh + mi*16 + lr)*40 + lk*8];
            al[mi] = *(const s16x8*)&Asl[(rh + mi*16 + lr)*40 + lk*8];
        }

        #pragma unroll
        for (int d = 0; d < 10; d++){
            const int cur = d % 3;
            if (d < 8){
                const int nx = (d + 2) % 3;
                const long t2 = (long)(jc*10 + d + 2)*64*32;
                pbh[nx] = *(const s16x8*)(W + t2 + laneoff);
            }
            f32x4 Cd[2];
            __builtin_amdgcn_s_setprio(1);
            #pragma unroll
            for (int mi = 0; mi < 2; mi++)
                Cd[mi] = mfma16(ah[mi], pbh[cur], Z4);
            #pragma unroll
            for (int mi = 0; mi < 2; mi++)
                Cd[mi] = mfma16(al[mi], pbh[cur], Cd[mi]);
            __builtin_amdgcn_s_setprio(0);
            #pragma unroll
            for (int mi = 0; mi < 2; mi++){
                f32x4 e4 = *(const f32x4*)&Et[d*64 + rh + mi*16 + lk*4];
                acc[mi] += e4 * Cd[mi];
            }
        }
    }

    #pragma unroll
    for (int mi = 0; mi < 2; mi++){
        int mrow = n0 + rh + mi*16 + lk*4;
        int o = ow + lr;
        #pragma unroll
        for (int r = 0; r < 4; r++){
            float v = acc[mi][r] + bias[(long)(mrow + r)*64 + o];
            v = tanhf(v);
            out[((long)b*2048 + mrow + r)*64 + o] = v;
        }
    }
}

// =====================================================================
extern "C" void kernel_launch(void* const* d_in, const int* in_sizes, int n_in,
                              void* d_out, int out_size, void* d_ws, size_t ws_size,
                              hipStream_t stream)
{
    const float* x   = (const float*)d_in[0];
    const float* st  = (const float*)d_in[1];
    const float* E   = (const float*)d_in[2];
    const float* gwp = (const float*)d_in[3];
    const float* gbp = (const float*)d_in[4];
    const float* uwp = (const float*)d_in[5];
    const float* ubp = (const float*)d_in[6];
    const float* lw  = (const float*)d_in[7];
    const float* lb  = (const float*)d_in[8];
    float* out = (float*)d_out;
    char* ws = (char*)d_ws;

    const size_t MB4 = 4194304;
    u16*   Sh   = (u16*)(ws);                 // 8 MB
    u16*   Sl   = (u16*)(ws + 2*MB4);         // 8 MB
    u16*   Xt   = (u16*)(ws + 4*MB4);         // 8 MB (gate X^T)
    u16*   G1t  = (u16*)(ws + 6*MB4);         // 8 MB
    float* G1row= (float*)(ws + 8*MB4);       // 16 MB
    float* G2row= (float*)(ws + 12*MB4);      // 16 MB
    float* zr   = (float*)(ws + 16*MB4);      // 8 MB
    u16*   Zt   = (u16*)(ws + 18*MB4);        // 4 MB (zr^T t-layout 1024x2048)
    u16*   G1zt = (u16*)(ws + 19*MB4);        // 4 MB
    float* G1z  = (float*)(ws + 20*MB4);      // 8 MB ([16][2048][64] f32)
    float* G2z  = (float*)(ws + 22*MB4);      // 8 MB
    char*  p    = ws + 24*MB4;
    u16* wg = (u16*)p;             p += 983040;
    u16* wu = (u16*)p;             p += 491520;
    float* bg = (float*)p;         p += 1048576;
    float* bu = (float*)p;         p += 524288;
    u16* lwt = (u16*)p;            p += 16384;

    // merged supports (2048 blocks) + prep (4449 blocks)
    k_prep<<<dim3(6497), dim3(256), 0, stream>>>(E, gwp, gbp, uwp, ubp, lw,
                                                 wg, wu, bg, bu, lwt, Sh, Sl);
    // coalesced gate X^T pack
    k_packx<<<dim3(256), dim3(256), 0, stream>>>(x, st, Xt);
    // gate diffusion (full N=2048)
    k_gemm<0,16><<<dim3(512), dim3(256), 0, stream>>>(Sh, Sl, Xt, G1t, G1row,
                                                      (const u16*)nullptr);
    k_gemm<1,16><<<dim3(512), dim3(256), 0, stream>>>(Sh, Sl, G1t, (u16*)nullptr,
                                                      G2row, Xt);
    // gate combine -> zr f32 + Zt (zr^T)
    k_combineG<<<dim3(512), dim3(512), 0, stream>>>(G1row, G2row, x, st,
                                                    wg, bg, E, zr, Zt, lwt, lb);
    // update diffusion, zr columns ONLY (N=1024): x-derived columns are
    // bit-identical to the gate pass's and reused from G1row/G2row.
    k_gemm<0,8><<<dim3(256), dim3(256), 0, stream>>>(Sh, Sl, Zt, G1zt, G1z,
                                                     (const u16*)nullptr);
    k_gemm<1,8><<<dim3(256), dim3(256), 0, stream>>>(Sh, Sl, G1zt, (u16*)nullptr,
                                                     G2z, Zt);
    // update combine -> out (tanh)
    k_combineU<<<dim3(512), dim3(512), 0, stream>>>(G1row, G2row, G1z, G2z,
                                                    x, zr, wu, bu, E, out);
}

// Round 14
// 329.715 us; speedup vs baseline: 1.0761x; 1.0231x over previous
//
#include <hip/hip_runtime.h>

typedef unsigned short u16;
typedef short s16x8 __attribute__((ext_vector_type(8)));
typedef _Float16 h16x8 __attribute__((ext_vector_type(8)));
typedef float f32x4 __attribute__((ext_vector_type(4)));
typedef u16 u16x4 __attribute__((ext_vector_type(4)));

#define DEV static __device__ __forceinline__

// ---------- f16 limb helpers (RTNE via v_cvt_f16_f32) ----------
DEV u16 f2h(float x){ union { _Float16 h; u16 u; } v; v.h = (_Float16)x; return v.u; }
DEV float h2f(u16 u){ union { u16 u; _Float16 h; } v; v.u = u; return (float)v.h; }
DEV void split_h(float x, u16& h, u16& l){
    h = f2h(x);
    l = f2h(x - h2f(h));
}
DEV h16x8 H8(s16x8 v){ union { s16x8 s; h16x8 h; } u; u.s = v; return u.h; }
DEV f32x4 mfma16(s16x8 a, s16x8 b, f32x4 c){
    return __builtin_amdgcn_mfma_f32_16x16x32_f16(H8(a), H8(b), c, 0, 0, 0);
}

// ---------- t-layout chunk swizzle (bits 3-5 of m XOR row&7) ----------
DEV int swz(int r, int m){ return (m & ~0x38) | ((((m >> 3) ^ r) & 7) << 3); }

// global -> LDS direct (16B per lane)
DEV void gll16(const u16* g, u16* l){
    __builtin_amdgcn_global_load_lds((const __attribute__((address_space(1))) void*)g,
                                     (__attribute__((address_space(3))) void*)l, 16, 0, 0);
}

// =====================================================================
// K_prep (merged): blocks 0..2047 = supports softmax rows; rest =
// weight/bias/lin_w prep.
// =====================================================================
__global__ __launch_bounds__(256) void k_prep(const float* __restrict__ E,
    const float* __restrict__ gwp, const float* __restrict__ gbp,
    const float* __restrict__ uwp, const float* __restrict__ ubp,
    const float* __restrict__ lw,
    u16* __restrict__ wg, u16* __restrict__ wu,
    float* __restrict__ bg, float* __restrict__ bu,
    u16* __restrict__ lwt,
    u16* __restrict__ Sh, u16* __restrict__ Sl)
{
    __shared__ float red[8];
    const int tid = threadIdx.x;
    if (blockIdx.x < 2048){
        const int n = blockIdx.x;
        const int w = tid >> 6, lane = tid & 63;
        float en[10];
        #pragma unroll
        for (int d = 0; d < 10; d++) en[d] = E[n*10 + d];
        float v[8];
        #pragma unroll
        for (int i = 0; i < 8; i++){
            int m = tid + i*256;
            const float* em = E + m*10;
            float s = 0.f;
            #pragma unroll
            for (int d = 0; d < 10; d++) s += en[d]*em[d];
            v[i] = fmaxf(s, 0.f);
        }
        float mx = v[0];
        #pragma unroll
        for (int i = 1; i < 8; i++) mx = fmaxf(mx, v[i]);
        #pragma unroll
        for (int off = 32; off > 0; off >>= 1) mx = fmaxf(mx, __shfl_xor(mx, off));
        if (lane == 0) red[w] = mx;
        __syncthreads();
        mx = fmaxf(fmaxf(red[0], red[1]), fmaxf(red[2], red[3]));
        __syncthreads();
        float sum = 0.f;
        #pragma unroll
        for (int i = 0; i < 8; i++){ v[i] = __expf(v[i] - mx); sum += v[i]; }
        #pragma unroll
        for (int off = 32; off > 0; off >>= 1) sum += __shfl_xor(sum, off);
        if (lane == 0) red[4 + w] = sum;
        __syncthreads();
        sum = red[4] + red[5] + red[6] + red[7];
        float inv = 1.f / sum;
        #pragma unroll
        for (int i = 0; i < 8; i++){
            float p = v[i] * inv;
            u16 h, l; split_h(p, h, l);
            int ms = swz(n, tid + i*256);
            Sh[n*2048 + ms] = h;
            Sl[n*2048 + ms] = l;
        }
        return;
    }
    long idx = (long)(blockIdx.x - 2048)*256 + tid;
    if (idx < 491520){                               // gate w -> [jc][d][128 o][32 k]
        int kk = (int)(idx & 31);
        int o  = (int)((idx >> 5) & 127);
        int r2 = (int)(idx >> 12);                   // 0..119
        int d = r2 % 10, jc = r2 / 10;
        int j = jc*32 + kk;                          // 0..383
        int k = j >> 7, i = j & 127;
        float v = gwp[(((d*3 + k)*128) + i)*128 + o];
        wg[idx] = f2h(v);
    } else if (idx < 737280){                        // upd w -> [jc][d][64 o][32 k]
        long t = idx - 491520;
        int kk = (int)(t & 31);
        int o  = (int)((t >> 5) & 63);
        int r2 = (int)(t >> 11);                     // 0..119
        int d = r2 % 10, jc = r2 / 10;
        int j = jc*32 + kk;
        int k = j >> 7, i = j & 127;
        float v = uwp[(((d*3 + k)*128) + i)*64 + o];
        wu[t] = f2h(v);
    } else if (idx < 999424){                        // bias_g [2048][128]
        long t = idx - 737280; int n = (int)(t >> 7), o = (int)(t & 127);
        float s = 0.f;
        #pragma unroll
        for (int d = 0; d < 10; d++) s += E[n*10+d]*gbp[d*128+o];
        bg[t] = s;
    } else if (idx < 1130496){                       // bias_u [2048][64]
        long t = idx - 999424; int n = (int)(t >> 6), o = (int)(t & 63);
        float s = 0.f;
        #pragma unroll
        for (int d = 0; d < 10; d++) s += E[n*10+d]*ubp[d*64+o];
        bu[t] = s;
    } else if (idx < 1138688){                       // lin_w [64 o][128 k] -> f16
        long t = idx - 1130496;
        lwt[t] = f2h(lw[t]);
    }
}

// =====================================================================
// k_packx: X_gate^T pack, coalesced (round-12 proven).
// =====================================================================
__global__ __launch_bounds__(256) void k_packx(const float* __restrict__ x,
                                               const float* __restrict__ state,
                                               u16* __restrict__ xt)
{
    __shared__ u16 T[64*264];
    const int tid = threadIdx.x;
    const int ct = blockIdx.x & 31;        // colG tile (64 wide)
    const int mt = blockIdx.x >> 5;        // m tile (256 tall)
    const int colG0 = ct << 6;
    const int m0 = mt << 8;
    const int b = colG0 >> 7, c0 = colG0 & 127;     // c0 in {0, 64}
    const float* src = (c0 < 64) ? (x + ((long)b*2048 + m0)*64)
                                 : (state + ((long)b*2048 + m0)*64);
    #pragma unroll
    for (int p = 0; p < 16; p++){
        int m = p*16 + (tid >> 4);
        int c4 = (tid & 15) << 2;
        f32x4 v = *(const f32x4*)(src + (long)m*64 + c4);
        #pragma unroll
        for (int q = 0; q < 4; q++)
            T[(c4 + q)*264 + m] = f2h(v[q]);
    }
    __syncthreads();
    #pragma unroll
    for (int p = 0; p < 8; p++){
        int cg = (tid >> 5) + p*8;
        int colG = colG0 + cg;
        int mc = (tid & 31) << 3;
        s16x8 val = *(const s16x8*)&T[cg*264 + mc];
        int ms = swz(colG, m0 + mc);
        *(s16x8*)(xt + (long)colG*2048 + ms) = val;
    }
}

// =====================================================================
// Gate diffusion GEMM (round-6 proven, 64x128 tile, 512 blocks).
// =====================================================================
template<int EPI>
__global__ __launch_bounds__(256) void k_gemm(
    const u16* __restrict__ Ah, const u16* __restrict__ Al,
    const u16* __restrict__ Bt,
    u16* __restrict__ Ot, float* __restrict__ Orow,
    const u16* __restrict__ Xt)
{
    __shared__ __attribute__((aligned(16))) u16 AsH[2][64*64];
    __shared__ __attribute__((aligned(16))) u16 AsL[2][64*64];
    __shared__ __attribute__((aligned(16))) u16 Bs[2][128*64];
    const int tid = threadIdx.x;
    const int xc = blockIdx.x & 7, ii = blockIdx.x >> 3;
    const int bm = ((xc & 3)*8 + (ii & 7)) << 6;     // 32 row-tiles
    const int bn = ((xc >> 2)*8 + (ii >> 3)) << 7;   // 16 col-tiles
    const int w = tid >> 6, lane = tid & 63;
    const int wm = (w & 1) << 5;                     // 32 rows per wave
    const int wn = (w >> 1) << 6;                    // 64 cols per wave
    const int lr = lane & 15, lk = lane >> 4;

    const int srow = tid >> 3, scol = (tid & 7) << 3;
    const long a0 = (long)(bm + srow)*2048 + scol;
    const long a1 = a0 + 32*2048;
    const long b0 = (long)(bn + srow)*2048 + scol;
    const long b1 = b0 + 32*2048;
    const long b2 = b0 + 64*2048;
    const long b3 = b0 + 96*2048;
    const int l0 = tid*8, l1 = tid*8 + 2048;

    const int c0 = (lk ^ (lr & 7)) << 3;
    const int c1 = c0 ^ 32;

#define STAGE(B, K) do { \
        gll16(Ah + a0 + (K), &AsH[B][l0]); \
        gll16(Ah + a1 + (K), &AsH[B][l1]); \
        gll16(Al + a0 + (K), &AsL[B][l0]); \
        gll16(Al + a1 + (K), &AsL[B][l1]); \
        gll16(Bt + b0 + (K), &Bs[B][l0]); \
        gll16(Bt + b1 + (K), &Bs[B][l1]); \
        gll16(Bt + b2 + (K), &Bs[B][l0 + 4096]); \
        gll16(Bt + b3 + (K), &Bs[B][l1 + 4096]); \
    } while(0)

    f32x4 acc[2][4];
    const f32x4 Z4 = {0.f, 0.f, 0.f, 0.f};
    #pragma unroll
    for (int i = 0; i < 2; i++)
        #pragma unroll
        for (int j = 0; j < 4; j++) acc[i][j] = Z4;

    STAGE(0, 0);
    __syncthreads();
    int cur = 0;
    for (int k0 = 0; k0 < 2048; k0 += 64){
        if (k0 + 64 < 2048) STAGE(cur ^ 1, k0 + 64);
        const u16* ah = AsH[cur];
        const u16* al = AsL[cur];
        const u16* bs = Bs[cur];
        #pragma unroll
        for (int s2 = 0; s2 < 2; s2++){
            const int cc = s2 ? c1 : c0;
            s16x8 bfv[4], af[2];
            #pragma unroll
            for (int ni = 0; ni < 4; ni++)
                bfv[ni] = *(const s16x8*)&bs[(wn + ni*16 + lr)*64 + cc];
            #pragma unroll
            for (int mi = 0; mi < 2; mi++)
                af[mi] = *(const s16x8*)&ah[(wm + mi*16 + lr)*64 + cc];
            #pragma unroll
            for (int mi = 0; mi < 2; mi++)
                #pragma unroll
                for (int ni = 0; ni < 4; ni++)
                    acc[mi][ni] = mfma16(af[mi], bfv[ni], acc[mi][ni]);
            #pragma unroll
            for (int mi = 0; mi < 2; mi++)
                af[mi] = *(const s16x8*)&al[(wm + mi*16 + lr)*64 + cc];
            #pragma unroll
            for (int mi = 0; mi < 2; mi++)
                #pragma unroll
                for (int ni = 0; ni < 4; ni++)
                    acc[mi][ni] = mfma16(af[mi], bfv[ni], acc[mi][ni]);
        }
        __syncthreads();
        cur ^= 1;
    }
#undef STAGE

    #pragma unroll
    for (int mi = 0; mi < 2; mi++){
        #pragma unroll
        for (int ni = 0; ni < 4; ni++){
            int i0 = bm + wm + mi*16 + lk*4;
            int j  = bn + wn + ni*16 + lr;
            f32x4 v = acc[mi][ni];
            if constexpr (EPI){
                u16x4 xh = *(const u16x4*)(Xt + (long)j*2048 + swz(j, i0));
                #pragma unroll
                for (int r = 0; r < 4; r++)
                    v[r] = 2.f*v[r] - h2f(xh[r]);
            }
            int bb = j >> 7, cc = j & 127;
            float* rp = Orow + ((long)bb*2048 + i0)*128 + cc;
            #pragma unroll
            for (int r = 0; r < 4; r++) rp[(long)r*128] = v[r];
            if constexpr (!EPI){
                u16x4 oh;
                #pragma unroll
                for (int r = 0; r < 4; r++) oh[r] = f2h(v[r]);
                *(u16x4*)(Ot + (long)j*2048 + swz(j, i0)) = oh;
            }
        }
    }
}

// =====================================================================
// Update (zr-only) diffusion GEMM: 64x64 tile, 32 row-tiles x 16
// col-tiles-of-64 = 512 blocks -> 2 blocks/CU restored (round-13's
// NCT=8 at 256 blocks = 1/CU exposed the barrier drains: ~45 us, no
// gain vs full width). Wave tile 32x32 (mi=2 x ni=2, acc 16 VGPR).
// Same staging/barrier/frag patterns; per-output MFMA order (s2 ->
// hi -> lo) identical -> bit-exact. LDS 48 KB/block.
// =====================================================================
template<int EPI>
__global__ __launch_bounds__(256) void k_gemmZ(
    const u16* __restrict__ Ah, const u16* __restrict__ Al,
    const u16* __restrict__ Bt,
    u16* __restrict__ Ot, float* __restrict__ Orow,
    const u16* __restrict__ Xt)
{
    __shared__ __attribute__((aligned(16))) u16 AsH[2][64*64];
    __shared__ __attribute__((aligned(16))) u16 AsL[2][64*64];
    __shared__ __attribute__((aligned(16))) u16 Bs[2][64*64];
    const int tid = threadIdx.x;
    // 8 XCDs x 64 blocks: 4x8 row-tiles, 2x8 col-tiles per XCD quadrant
    const int xc = blockIdx.x & 7, ii = blockIdx.x >> 3;
    const int bm = ((xc & 3)*8 + (ii & 7)) << 6;     // 32 row-tiles (64 rows)
    const int bn = ((xc >> 2)*8 + (ii >> 3)) << 6;   // 16 col-tiles (64 cols)
    const int w = tid >> 6, lane = tid & 63;
    const int wm = (w & 1) << 5;                     // 32 rows per wave
    const int wn = (w >> 1) << 5;                    // 32 cols per wave
    const int lr = lane & 15, lk = lane >> 4;

    const int srow = tid >> 3, scol = (tid & 7) << 3;
    const long a0 = (long)(bm + srow)*2048 + scol;
    const long a1 = a0 + 32*2048;
    const long b0 = (long)(bn + srow)*2048 + scol;
    const long b1 = b0 + 32*2048;
    const int l0 = tid*8, l1 = tid*8 + 2048;

    const int c0 = (lk ^ (lr & 7)) << 3;
    const int c1 = c0 ^ 32;

#define STAGEZ(B, K) do { \
        gll16(Ah + a0 + (K), &AsH[B][l0]); \
        gll16(Ah + a1 + (K), &AsH[B][l1]); \
        gll16(Al + a0 + (K), &AsL[B][l0]); \
        gll16(Al + a1 + (K), &AsL[B][l1]); \
        gll16(Bt + b0 + (K), &Bs[B][l0]); \
        gll16(Bt + b1 + (K), &Bs[B][l1]); \
    } while(0)

    f32x4 acc[2][2];
    const f32x4 Z4 = {0.f, 0.f, 0.f, 0.f};
    #pragma unroll
    for (int i = 0; i < 2; i++)
        #pragma unroll
        for (int j = 0; j < 2; j++) acc[i][j] = Z4;

    STAGEZ(0, 0);
    __syncthreads();
    int cur = 0;
    for (int k0 = 0; k0 < 2048; k0 += 64){
        if (k0 + 64 < 2048) STAGEZ(cur ^ 1, k0 + 64);
        const u16* ah = AsH[cur];
        const u16* al = AsL[cur];
        const u16* bs = Bs[cur];
        #pragma unroll
        for (int s2 = 0; s2 < 2; s2++){
            const int cc = s2 ? c1 : c0;
            s16x8 bfv[2], af[2];
            #pragma unroll
            for (int ni = 0; ni < 2; ni++)
                bfv[ni] = *(const s16x8*)&bs[(wn + ni*16 + lr)*64 + cc];
            #pragma unroll
            for (int mi = 0; mi < 2; mi++)
                af[mi] = *(const s16x8*)&ah[(wm + mi*16 + lr)*64 + cc];
            #pragma unroll
            for (int mi = 0; mi < 2; mi++)
                #pragma unroll
                for (int ni = 0; ni < 2; ni++)
                    acc[mi][ni] = mfma16(af[mi], bfv[ni], acc[mi][ni]);
            #pragma unroll
            for (int mi = 0; mi < 2; mi++)
                af[mi] = *(const s16x8*)&al[(wm + mi*16 + lr)*64 + cc];
            #pragma unroll
            for (int mi = 0; mi < 2; mi++)
                #pragma unroll
                for (int ni = 0; ni < 2; ni++)
                    acc[mi][ni] = mfma16(af[mi], bfv[ni], acc[mi][ni]);
        }
        __syncthreads();
        cur ^= 1;
    }
#undef STAGEZ

    #pragma unroll
    for (int mi = 0; mi < 2; mi++){
        #pragma unroll
        for (int ni = 0; ni < 2; ni++){
            int i0 = bm + wm + mi*16 + lk*4;
            int j  = bn + wn + ni*16 + lr;       // colZ in [0,1024)
            f32x4 v = acc[mi][ni];
            if constexpr (EPI){
                u16x4 xh = *(const u16x4*)(Xt + (long)j*2048 + swz(j, i0));
                #pragma unroll
                for (int r = 0; r < 4; r++)
                    v[r] = 2.f*v[r] - h2f(xh[r]);
            }
            int bb = j >> 6, cc = j & 63;
            float* rp = Orow + ((long)bb*2048 + i0)*64 + cc;
            #pragma unroll
            for (int r = 0; r < 4; r++) rp[(long)r*64] = v[r];
            if constexpr (!EPI){
                u16x4 oh;
                #pragma unroll
                for (int r = 0; r < 4; r++) oh[r] = f2h(v[r]);
                *(u16x4*)(Ot + (long)j*2048 + swz(j, i0)) = oh;
            }
        }
    }
}

// =====================================================================
// Gate combine (round-12 proven, 512 thr / 8 waves, o-split, setprio).
// Fused epilogue: zr = Zg@lw^T + lb -> zr f32 rows + Zt (zr^T t-layout).
// absmax canary 0.01513672.
// =====================================================================
__global__ __launch_bounds__(512) void k_combineG(
    const float* __restrict__ G1r, const float* __restrict__ G2r,
    const float* __restrict__ x, const float* __restrict__ second,
    const u16* __restrict__ W,
    const float* __restrict__ bias, const float* __restrict__ E,
    float* __restrict__ out, u16* __restrict__ Zt,
    const u16* __restrict__ lwt, const float* __restrict__ lb)
{
    __shared__ u16 Ash[64*40], Asl[64*40];
    __shared__ float Et[640];
    __shared__ u16 Zh[64*136], Zl[64*136];
    const int tid = threadIdx.x, bid = blockIdx.x;
    const int b = bid >> 5, n0 = (bid & 31) << 6;
    const int w = tid >> 6, lane = tid & 63;
    const int wo = w << 4;                        // wave's 16-o stripe
    const int lr = lane & 15, lk = lane >> 4;

    for (int i = tid; i < 640; i += 512)
        Et[i] = E[(n0 + (i & 63))*10 + (i >> 6)];

    const f32x4 Z4 = {0.f, 0.f, 0.f, 0.f};
    f32x4 acc[4];
    #pragma unroll
    for (int mi = 0; mi < 4; mi++) acc[mi] = Z4;

    const long rowbase = (long)b*2048 + n0;
    const int laneoff = (wo + lr)*32 + lk*8;      // u16 offset within W tile

    s16x8 pbh[3];

    for (int jc = 0; jc < 12; jc++){
        {
            const long t0 = (long)(jc*10 + 0)*128*32;
            const long t1 = (long)(jc*10 + 1)*128*32;
            pbh[0] = *(const s16x8*)(W + t0 + laneoff);
            pbh[1] = *(const s16x8*)(W + t1 + laneoff);
        }
        __syncthreads();   // prior jc's A-frag reads done
        // ---- stage A (512 thr: one f32x4 per thread) ----
        {
            const float* src; int stride;
            if (jc < 4){
                int col0 = jc*32;
                src = (col0 < 64) ? (x + rowbase*64 + col0)
                                  : (second + rowbase*64 + (col0 - 64));
                stride = 64;
            } else if (jc < 8){
                src = G1r + rowbase*128 + (jc-4)*32; stride = 128;
            } else {
                src = G2r + rowbase*128 + (jc-8)*32; stride = 128;
            }
            int row = tid >> 3, c4 = (tid & 7)*4;
            f32x4 s0 = *(const f32x4*)(src + (long)row*stride + c4);
            u16x4 vh, vl;
            #pragma unroll
            for (int t = 0; t < 4; t++){
                u16 h,l; split_h(s0[t], h, l); vh[t]=h; vl[t]=l;
            }
            *(u16x4*)&Ash[row*40 + c4] = vh;
            *(u16x4*)&Asl[row*40 + c4] = vl;
        }
        __syncthreads();

        s16x8 ah[4], al[4];
        #pragma unroll
        for (int mi = 0; mi < 4; mi++){
            ah[mi] = *(const s16x8*)&Ash[(mi*16 + lr)*40 + lk*8];
            al[mi] = *(const s16x8*)&Asl[(mi*16 + lr)*40 + lk*8];
        }

        #pragma unroll
        for (int d = 0; d < 10; d++){
            const int cur = d % 3;
            if (d < 8){
                const int nx = (d + 2) % 3;
                const long t2 = (long)(jc*10 + d + 2)*128*32;
                pbh[nx] = *(const s16x8*)(W + t2 + laneoff);
            }
            f32x4 Cd[4];
            __builtin_amdgcn_s_setprio(1);
            #pragma unroll
            for (int mi = 0; mi < 4; mi++)
                Cd[mi] = mfma16(ah[mi], pbh[cur], Z4);
            #pragma unroll
            for (int mi = 0; mi < 4; mi++)
                Cd[mi] = mfma16(al[mi], pbh[cur], Cd[mi]);
            __builtin_amdgcn_s_setprio(0);
            #pragma unroll
            for (int mi = 0; mi < 4; mi++){
                f32x4 e4 = *(const f32x4*)&Et[d*64 + mi*16 + lk*4];
                acc[mi] += e4 * Cd[mi];
            }
        }
    }

    // ---- fused: Zg = sigmoid(acc+bias) -> LDS limbs ----
    #pragma unroll
    for (int mi = 0; mi < 4; mi++){
        int lrow = mi*16 + lk*4;
        int o = wo + lr;
        #pragma unroll
        for (int r = 0; r < 4; r++){
            float v = acc[mi][r] + bias[(long)(n0 + lrow + r)*128 + o];
            v = 1.f/(1.f + __expf(-v));
            u16 h, l; split_h(v, h, l);
            Zh[(lrow + r)*136 + o] = h;
            Zl[(lrow + r)*136 + o] = l;
        }
    }
    __syncthreads();
    // ---- zr = Zg @ lw^T + lb ; wave w: o-stripe (w&3)*16, rows (w>>2)*32 ----
    f32x4 az[2] = {Z4, Z4};
    const int ow = (w & 3) << 4;
    const int rh = (w >> 2) << 5;
    #pragma unroll
    for (int ks = 0; ks < 4; ks++){
        s16x8 bw = *(const s16x8*)(lwt + (ow + lr)*128 + ks*32 + lk*8);
        #pragma unroll
        for (int mi = 0; mi < 2; mi++){
            s16x8 zh = *(const s16x8*)&Zh[(rh + mi*16 + lr)*136 + ks*32 + lk*8];
            az[mi] = mfma16(zh, bw, az[mi]);
        }
        #pragma unroll
        for (int mi = 0; mi < 2; mi++){
            s16x8 zl = *(const s16x8*)&Zl[(rh + mi*16 + lr)*136 + ks*32 + lk*8];
            az[mi] = mfma16(zl, bw, az[mi]);
        }
    }
    const float lbv = lb[ow + lr];
    const int colZ = b*64 + ow + lr;                 // zr^T row in [0,1024)
    #pragma unroll
    for (int mi = 0; mi < 2; mi++){
        int mrow = n0 + rh + mi*16 + lk*4;
        u16x4 tq;
        #pragma unroll
        for (int r = 0; r < 4; r++){
            float v = az[mi][r] + lbv;
            out[((long)b*2048 + mrow + r)*64 + ow + lr] = v;   // zr f32 rows
            tq[r] = f2h(v);
        }
        *(u16x4*)(Zt + (long)colZ*2048 + swz(colZ, mrow)) = tq; // zr^T t-layout
    }
}

// =====================================================================
// Update combine (round-13 proven): x-derived chunks from the gate
// pass's G1row/G2row cols 0-63 (bit-identical), zr-derived from G1z/G2z.
// =====================================================================
__global__ __launch_bounds__(512) void k_combineU(
    const float* __restrict__ G1r, const float* __restrict__ G2r,
    const float* __restrict__ G1z, const float* __restrict__ G2z,
    const float* __restrict__ x, const float* __restrict__ zr,
    const u16* __restrict__ W,
    const float* __restrict__ bias, const float* __restrict__ E,
    float* __restrict__ out)
{
    __shared__ u16 Ash[64*40], Asl[64*40];
    __shared__ float Et[640];
    const int tid = threadIdx.x, bid = blockIdx.x;
    const int b = bid >> 5, n0 = (bid & 31) << 6;
    const int w = tid >> 6, lane = tid & 63;
    const int ow = (w & 3) << 4;                  // wave's 16-o stripe
    const int rh = (w >> 2) << 5;                 // wave's 32-row half
    const int lr = lane & 15, lk = lane >> 4;

    for (int i = tid; i < 640; i += 512)
        Et[i] = E[(n0 + (i & 63))*10 + (i >> 6)];

    const f32x4 Z4 = {0.f, 0.f, 0.f, 0.f};
    f32x4 acc[2];
    #pragma unroll
    for (int mi = 0; mi < 2; mi++) acc[mi] = Z4;

    const long rowbase = (long)b*2048 + n0;
    const int laneoff = (ow + lr)*32 + lk*8;      // u16 offset in [64 o][32 k] tile

    s16x8 pbh[3];

    for (int jc = 0; jc < 12; jc++){
        {
            const long t0 = (long)(jc*10 + 0)*64*32;
            const long t1 = (long)(jc*10 + 1)*64*32;
            pbh[0] = *(const s16x8*)(W + t0 + laneoff);
            pbh[1] = *(const s16x8*)(W + t1 + laneoff);
        }
        __syncthreads();
        // ---- stage A (512 thr: one f32x4 per thread) ----
        {
            const float* src; int stride;
            switch (jc >> 1){
                case 0: src = x   + rowbase*64  + (jc&1)*32;  stride = 64;  break;
                case 1: src = zr  + rowbase*64  + (jc&1)*32;  stride = 64;  break;
                case 2: src = G1r + rowbase*128 + (jc&1)*32;  stride = 128; break;
                case 3: src = G1z + rowbase*64  + (jc&1)*32;  stride = 64;  break;
                case 4: src = G2r + rowbase*128 + (jc&1)*32;  stride = 128; break;
                default:src = G2z + rowbase*64  + (jc&1)*32;  stride = 64;  break;
            }
            int row = tid >> 3, c4 = (tid & 7)*4;
            f32x4 s0 = *(const f32x4*)(src + (long)row*stride + c4);
            u16x4 vh, vl;
            #pragma unroll
            for (int t = 0; t < 4; t++){
                u16 h,l; split_h(s0[t], h, l); vh[t]=h; vl[t]=l;
            }
            *(u16x4*)&Ash[row*40 + c4] = vh;
            *(u16x4*)&Asl[row*40 + c4] = vl;
        }
        __syncthreads();

        s16x8 ah[2], al[2];
        #pragma unroll
        for (int mi = 0; mi < 2; mi++){
            ah[mi] = *(const s16x8*)&Ash[(rh + mi*16 + lr)*40 + lk*8];
            al[mi] = *(const s16x8*)&Asl[(rh + mi*16 + lr)*40 + lk*8];
        }

        #pragma unroll
        for (int d = 0; d < 10; d++){
            const int cur = d % 3;
            if (d < 8){
                const int nx = (d + 2) % 3;
                const long t2 = (long)(jc*10 + d + 2)*64*32;
                pbh[nx] = *(const s16x8*)(W + t2 + laneoff);
            }
            f32x4 Cd[2];
            __builtin_amdgcn_s_setprio(1);
            #pragma unroll
            for (int mi = 0; mi < 2; mi++)
                Cd[mi] = mfma16(ah[mi], pbh[cur], Z4);
            #pragma unroll
            for (int mi = 0; mi < 2; mi++)
                Cd[mi] = mfma16(al[mi], pbh[cur], Cd[mi]);
            __builtin_amdgcn_s_setprio(0);
            #pragma unroll
            for (int mi = 0; mi < 2; mi++){
                f32x4 e4 = *(const f32x4*)&Et[d*64 + rh + mi*16 + lk*4];
                acc[mi] += e4 * Cd[mi];
            }
        }
    }

    #pragma unroll
    for (int mi = 0; mi < 2; mi++){
        int mrow = n0 + rh + mi*16 + lk*4;
        int o = ow + lr;
        #pragma unroll
        for (int r = 0; r < 4; r++){
            float v = acc[mi][r] + bias[(long)(mrow + r)*64 + o];
            v = tanhf(v);
            out[((long)b*2048 + mrow + r)*64 + o] = v;
        }
    }
}

// =====================================================================
extern "C" void kernel_launch(void* const* d_in, const int* in_sizes, int n_in,
                              void* d_out, int out_size, void* d_ws, size_t ws_size,
                              hipStream_t stream)
{
    const float* x   = (const float*)d_in[0];
    const float* st  = (const float*)d_in[1];
    const float* E   = (const float*)d_in[2];
    const float* gwp = (const float*)d_in[3];
    const float* gbp = (const float*)d_in[4];
    const float* uwp = (const float*)d_in[5];
    const float* ubp = (const float*)d_in[6];
    const float* lw  = (const float*)d_in[7];
    const float* lb  = (const float*)d_in[8];
    float* out = (float*)d_out;
    char* ws = (char*)d_ws;

    const size_t MB4 = 4194304;
    u16*   Sh   = (u16*)(ws);                 // 8 MB
    u16*   Sl   = (u16*)(ws + 2*MB4);         // 8 MB
    u16*   Xt   = (u16*)(ws + 4*MB4);         // 8 MB (gate X^T)
    u16*   G1t  = (u16*)(ws + 6*MB4);         // 8 MB
    float* G1row= (float*)(ws + 8*MB4);       // 16 MB
    float* G2row= (float*)(ws + 12*MB4);      // 16 MB
    float* zr   = (float*)(ws + 16*MB4);      // 8 MB
    u16*   Zt   = (u16*)(ws + 18*MB4);        // 4 MB (zr^T t-layout 1024x2048)
    u16*   G1zt = (u16*)(ws + 19*MB4);        // 4 MB
    float* G1z  = (float*)(ws + 20*MB4);      // 8 MB ([16][2048][64] f32)
    float* G2z  = (float*)(ws + 22*MB4);      // 8 MB
    char*  p    = ws + 24*MB4;
    u16* wg = (u16*)p;             p += 983040;
    u16* wu = (u16*)p;             p += 491520;
    float* bg = (float*)p;         p += 1048576;
    float* bu = (float*)p;         p += 524288;
    u16* lwt = (u16*)p;            p += 16384;

    // merged supports (2048 blocks) + prep (4449 blocks)
    k_prep<<<dim3(6497), dim3(256), 0, stream>>>(E, gwp, gbp, uwp, ubp, lw,
                                                 wg, wu, bg, bu, lwt, Sh, Sl);
    // coalesced gate X^T pack
    k_packx<<<dim3(256), dim3(256), 0, stream>>>(x, st, Xt);
    // gate diffusion (full N=2048)
    k_gemm<0><<<dim3(512), dim3(256), 0, stream>>>(Sh, Sl, Xt, G1t, G1row,
                                                   (const u16*)nullptr);
    k_gemm<1><<<dim3(512), dim3(256), 0, stream>>>(Sh, Sl, G1t, (u16*)nullptr,
                                                   G2row, Xt);
    // gate combine -> zr f32 + Zt (zr^T)
    k_combineG<<<dim3(512), dim3(512), 0, stream>>>(G1row, G2row, x, st,
                                                    wg, bg, E, zr, Zt, lwt, lb);
    // update diffusion, zr columns only, 64x64 tiles -> 512 blocks (2/CU)
    k_gemmZ<0><<<dim3(512), dim3(256), 0, stream>>>(Sh, Sl, Zt, G1zt, G1z,
                                                    (const u16*)nullptr);
    k_gemmZ<1><<<dim3(512), dim3(256), 0, stream>>>(Sh, Sl, G1zt, (u16*)nullptr,
                                                    G2z, Zt);
    // update combine -> out (tanh)
    k_combineU<<<dim3(512), dim3(512), 0, stream>>>(G1row, G2row, G1z, G2z,
                                                    x, zr, wu, bu, E, out);
}